// Round 10
// baseline (64.854 us; speedup 1.0000x reference)
//
#include <hip/hip_runtime.h>

#define E  1024
#define H  64
#define BB 8
#define TT 2048

typedef __attribute__((ext_vector_type(8)))  short bf16x8;
typedef __attribute__((ext_vector_type(4)))  float f32x4;
typedef __attribute__((ext_vector_type(16))) float f32x16;
typedef __attribute__((ext_vector_type(8)))  short short8;
typedef __attribute__((ext_vector_type(4)))  short short4v;
typedef __attribute__((ext_vector_type(4)))  unsigned u32x4;

__device__ __forceinline__ short f2bf(float f) {
    union { float f; unsigned u; } v; v.f = f;
    unsigned r = v.u + 0x7FFFu + ((v.u >> 16) & 1u);   // RNE
    return (short)(r >> 16);
}

// fast 2^x via the HW transcendental (no HIP __exp2f intrinsic exists)
__device__ __forceinline__ float fexp2(float x) {
    float r;
    asm("v_exp_f32 %0, %1" : "=v"(r) : "v"(x));
    return r;
}

// 8 fp32 -> bf16x8 via 4x v_cvt_pk_bf16_f32 (proven in attn_v8)
__device__ __forceinline__ bf16x8 cvt8(float4 a0, float4 a1) {
    unsigned w0, w1, w2, w3;
    asm("v_cvt_pk_bf16_f32 %0, %1, %2" : "=v"(w0) : "v"(a0.x), "v"(a0.y));
    asm("v_cvt_pk_bf16_f32 %0, %1, %2" : "=v"(w1) : "v"(a0.z), "v"(a0.w));
    asm("v_cvt_pk_bf16_f32 %0, %1, %2" : "=v"(w2) : "v"(a1.x), "v"(a1.y));
    asm("v_cvt_pk_bf16_f32 %0, %1, %2" : "=v"(w3) : "v"(a1.z), "v"(a1.w));
    u32x4 u = {w0, w1, w2, w3};
    bf16x8 r;
    __builtin_memcpy(&r, &u, 16);
    return r;
}

// ---- pack W into B-fragment layout for mfma_f32_16x16x32_bf16 ----
__global__ __launch_bounds__(256)
void pack_w(const float* __restrict__ Wq, const float* __restrict__ Wk,
            const float* __restrict__ Wv, short* __restrict__ Wb)
{
    const int t  = blockIdx.x * 256 + threadIdx.x;   // 24576 total
    const int l  = t & 63;
    const int f  = (t >> 6) % 12;
    const int kc = t / 768;                          // kchunk 0..31
    const float* W = (f < 4) ? Wq : ((f < 8) ? Wk : Wv);
    const int e0 = kc * 32 + ((l >> 4) << 3);
    const int n  = ((f & 3) << 4) + (l & 15);
    short8 o;
    #pragma unroll
    for (int j = 0; j < 8; ++j) o[j] = f2bf(W[(e0 + j) * 64 + n]);
    *(short8*)&Wb[(size_t)t * 8] = o;
}

// ---- proj v2: 4-way split-K, 16-row blocks, x prefetched 1 pair ahead ----
// grid 1024 x 256 thr; wave kh = wid (K slice of 256 = 4 pairs of 2 kc).
__global__ __launch_bounds__(256)
void proj_v2(const float* __restrict__ x, const short* __restrict__ Wb,
             short* __restrict__ q, short* __restrict__ k, short* __restrict__ vt)
{
    __shared__ float part[3][12][64][4];   // 18 KB: kh=1..3 partials
    const int t   = threadIdx.x;
    const int l   = t & 63;
    const int kh  = t >> 6;                // 0..3
    const long row0 = (long)blockIdx.x * 16;
    const int l15 = l & 15, g = l >> 4;

    f32x4 acc[12];
    #pragma unroll
    for (int f = 0; f < 12; ++f) acc[f] = (f32x4){0.f, 0.f, 0.f, 0.f};

    const float* xp  = x + (row0 + l15) * E + kh * 256 + g * 8;
    const short* wb0 = Wb + (size_t)(kh * 8) * 12 * 512 + (size_t)l * 8;

    // prefetch pair 0 (2 kc = 64 floats per row slice)
    float4 a0 = *(const float4*)(xp);
    float4 a1 = *(const float4*)(xp + 4);
    float4 a2 = *(const float4*)(xp + 32);
    float4 a3 = *(const float4*)(xp + 36);

    #pragma unroll
    for (int pp = 0; pp < 4; ++pp) {
        float4 b0, b1, b2, b3;
        if (pp < 3) {   // issue next-pair loads before compute
            const float* xn = xp + (pp + 1) * 64;
            b0 = *(const float4*)(xn);
            b1 = *(const float4*)(xn + 4);
            b2 = *(const float4*)(xn + 32);
            b3 = *(const float4*)(xn + 36);
        }
        bf16x8 af0 = cvt8(a0, a1);
        bf16x8 af1 = cvt8(a2, a3);
        const short* wp = wb0 + (size_t)(pp * 2) * 12 * 512;
        #pragma unroll
        for (int f = 0; f < 12; ++f) {
            bf16x8 bf = *(const bf16x8*)(wp + (size_t)f * 512);
            acc[f] = __builtin_amdgcn_mfma_f32_16x16x32_bf16(af0, bf, acc[f], 0, 0, 0);
        }
        wp += 12 * 512;
        #pragma unroll
        for (int f = 0; f < 12; ++f) {
            bf16x8 bf = *(const bf16x8*)(wp + (size_t)f * 512);
            acc[f] = __builtin_amdgcn_mfma_f32_16x16x32_bf16(af1, bf, acc[f], 0, 0, 0);
        }
        a0 = b0; a1 = b1; a2 = b2; a3 = b3;
    }

    if (kh > 0) {
        #pragma unroll
        for (int f = 0; f < 12; ++f)
            *(f32x4*)&part[kh - 1][f][l][0] = acc[f];
    }
    __syncthreads();
    if (kh == 0) {
        #pragma unroll
        for (int f = 0; f < 12; ++f) {
            acc[f] += *(const f32x4*)&part[0][f][l][0];
            acc[f] += *(const f32x4*)&part[1][f][l][0];
            acc[f] += *(const f32x4*)&part[2][f][l][0];
        }
        #pragma unroll
        for (int f = 0; f < 12; ++f) {
            const int m = f >> 2;
            const int h = ((f & 3) << 4) + l15;
            if (m == 2) {
                // Vt[b][h][t], pack 4 consecutive t into one 8B store
                const long row = row0 + g * 4;
                const long bb = row >> 11;
                const int  t0 = (int)(row & 2047);
                short4v pkt;
                #pragma unroll
                for (int r = 0; r < 4; ++r) pkt[r] = f2bf(acc[f][r]);
                *(short4v*)&vt[(bb * 64 + h) * TT + t0] = pkt;
            } else {
                short* base = (m == 0) ? q : k;
                // fold 1/sqrt(H) AND log2(e) into q -> softmax uses exp2
                const float sc = (m == 0) ? (0.125f * 1.44269504f) : 1.0f;
                #pragma unroll
                for (int r = 0; r < 4; ++r) {
                    const long row = row0 + g * 4 + r;
                    base[row * 64 + h] = f2bf(acc[f][r] * sc);
                }
            }
        }
    }
}

// ---- 32x32 swapped-QK^T flash attention (T12: cvt_pk + permlane32_swap) ----
// Grid 256 = 32 tile-pairs x 8 batches (b = bid&7 -> XCD pin). Block = 512
// thr = 8 waves on tile pair (pr, 63-pr) = 65 chunks of 32 kv; waves split
// proportionally (8-10 chunks each). Swapped QK^T: lane owns q-row (L&31),
// P^T col in regs -> lane-local softmax, in-register P->bf16 B-frags.
__global__ __launch_bounds__(512)
void attn_v8(const short* __restrict__ qg,
             const short* __restrict__ kg,
             const short* __restrict__ vtg,
             float* __restrict__ out)
{
    __shared__ float Op[8][32][66];      // per-wave O^T partials [w][q][h]
    __shared__ float Ml[8][32][2];       // per-wave (m, l)

    const int t   = threadIdx.x;
    const int L   = t & 63;
    const int w   = t >> 6;
    const int bid = blockIdx.x;
    const int b   = bid & 7;             // XCD pin
    const int pr  = bid >> 3;            // pair 0..31
    const int l31 = L & 31, hi = L >> 5;

    const int stA = pr, stB = 63 - pr;
    const int nA = stA + 1;
    int WA = (8 * nA + 32) / 65;         // round(8*nA/65)
    WA = WA < 1 ? 1 : (WA > 7 ? 7 : WA);
    const int WB = 8 - WA;

    const bool isB  = (w >= WA);
    const int  st   = isB ? stB : stA;
    const int  q0   = st * 32;
    const int  strd = isB ? WB : WA;
    const int  c0   = isB ? (w - WA) : w;

    // Q B-frags: col=q=l31, k=e=es*16+hi*8+j
    bf16x8 qf[4];
    {
        const short* qp = qg + ((long)b * TT + q0 + l31) * 64 + hi * 8;
        qf[0] = *(const bf16x8*)(qp);
        qf[1] = *(const bf16x8*)(qp + 16);
        qf[2] = *(const bf16x8*)(qp + 32);
        qf[3] = *(const bf16x8*)(qp + 48);
    }

    f32x16 o0 = {}, o1 = {};
    float mrun = -1e30f, lrun = 0.f;

    const short* kbase = kg  + ((long)b * TT + l31) * 64 + hi * 8;
    const short* vbase = vtg + ((long)b * 64 + l31) * TT + hi * 8;

    for (int ci = c0; ci <= st; ci += strd) {
        const int kvs = ci * 32;
        // K A-frags: row=kv=kvs+l31, k=e (contiguous 16B)
        const short* kp = kbase + (long)kvs * 64;
        bf16x8 kf0 = *(const bf16x8*)(kp);
        bf16x8 kf1 = *(const bf16x8*)(kp + 16);
        bf16x8 kf2 = *(const bf16x8*)(kp + 32);
        bf16x8 kf3 = *(const bf16x8*)(kp + 48);
        // V A-frags issued early: row=h=nf*32+l31, k=kv slice
        const short* vp = vbase + kvs;
        bf16x8 vf00 = *(const bf16x8*)(vp);
        bf16x8 vf01 = *(const bf16x8*)(vp + 16);
        bf16x8 vf10 = *(const bf16x8*)(vp + 32 * TT);
        bf16x8 vf11 = *(const bf16x8*)(vp + 32 * TT + 16);

        // ---- QK^T swapped: S^T[kv,q]; D: col=q=l31, row=crow(r,hi) ----
        f32x16 s = {};
        __builtin_amdgcn_s_setprio(1);
        s = __builtin_amdgcn_mfma_f32_32x32x16_bf16(kf0, qf[0], s, 0, 0, 0);
        s = __builtin_amdgcn_mfma_f32_32x32x16_bf16(kf1, qf[1], s, 0, 0, 0);
        s = __builtin_amdgcn_mfma_f32_32x32x16_bf16(kf2, qf[2], s, 0, 0, 0);
        s = __builtin_amdgcn_mfma_f32_32x32x16_bf16(kf3, qf[3], s, 0, 0, 0);
        __builtin_amdgcn_s_setprio(0);

        // ---- causal mask: only the diagonal chunk ----
        if (kvs == q0) {
            #pragma unroll
            for (int r = 0; r < 16; ++r) {
                const int crow = (r & 3) + 8 * (r >> 2) + 4 * hi;
                if (crow > l31) s[r] = -1e30f;
            }
        }
        // ---- lane-local row max (q-row = l31) + hi-half exchange ----
        float m01 = fmaxf(s[0], s[1]),   m23 = fmaxf(s[2], s[3]);
        float m45 = fmaxf(s[4], s[5]),   m67 = fmaxf(s[6], s[7]);
        float m89 = fmaxf(s[8], s[9]),   mab = fmaxf(s[10], s[11]);
        float mcd = fmaxf(s[12], s[13]), mef = fmaxf(s[14], s[15]);
        float mloc = fmaxf(fmaxf(fmaxf(m01, m23), fmaxf(m45, m67)),
                           fmaxf(fmaxf(m89, mab), fmaxf(mcd, mef)));
        mloc = fmaxf(mloc, __shfl_xor(mloc, 32));
        // ---- defer-max rescale (THR = 8 in exp2 units) ----
        if (__any(mloc > mrun + 8.f)) {
            const float mnew = fmaxf(mrun, mloc);
            const float a = fexp2(mrun - mnew);
            mrun = mnew;
            lrun *= a;
            #pragma unroll
            for (int r = 0; r < 16; ++r) { o0[r] *= a; o1[r] *= a; }
        }
        // ---- p = exp2(s - m) in place; lane-local sum ----
        #pragma unroll
        for (int r = 0; r < 16; ++r) s[r] = fexp2(s[r] - mrun);
        {
            float s01 = (s[0] + s[1]) + (s[2] + s[3]);
            float s23 = (s[4] + s[5]) + (s[6] + s[7]);
            float s45 = (s[8] + s[9]) + (s[10] + s[11]);
            float s67 = (s[12] + s[13]) + (s[14] + s[15]);
            float lsum = (s01 + s23) + (s45 + s67);
            lsum += __shfl_xor(lsum, 32);
            lrun += lsum;
        }
        // ---- in-register P->bf16 B-frags: 8 cvt_pk + 4 permlane32_swap ----
        unsigned wv[8];
        #pragma unroll
        for (int i = 0; i < 8; ++i)
            asm("v_cvt_pk_bf16_f32 %0, %1, %2" : "=v"(wv[i]) : "v"(s[2 * i]), "v"(s[2 * i + 1]));
        unsigned p00 = wv[0], p02 = wv[2];   // ks=0: words 0,2
        unsigned p01 = wv[1], p03 = wv[3];   // ks=0: words 1,3
        unsigned p10 = wv[4], p12 = wv[6];   // ks=1
        unsigned p11 = wv[5], p13 = wv[7];
        asm("v_permlane32_swap_b32 %0, %1" : "+v"(p00), "+v"(p02));
        asm("v_permlane32_swap_b32 %0, %1" : "+v"(p01), "+v"(p03));
        asm("v_permlane32_swap_b32 %0, %1" : "+v"(p10), "+v"(p12));
        asm("v_permlane32_swap_b32 %0, %1" : "+v"(p11), "+v"(p13));
        u32x4 pb0u = {p00, p01, p02, p03};
        u32x4 pb1u = {p10, p11, p12, p13};
        bf16x8 pb0, pb1;
        __builtin_memcpy(&pb0, &pb0u, 16);
        __builtin_memcpy(&pb1, &pb1u, 16);
        // ---- PV: O^T[h,q] += V^T x P^T ----
        __builtin_amdgcn_s_setprio(1);
        o0 = __builtin_amdgcn_mfma_f32_32x32x16_bf16(vf00, pb0, o0, 0, 0, 0);
        o0 = __builtin_amdgcn_mfma_f32_32x32x16_bf16(vf01, pb1, o0, 0, 0, 0);
        o1 = __builtin_amdgcn_mfma_f32_32x32x16_bf16(vf10, pb0, o1, 0, 0, 0);
        o1 = __builtin_amdgcn_mfma_f32_32x32x16_bf16(vf11, pb1, o1, 0, 0, 0);
        __builtin_amdgcn_s_setprio(0);
    }

    // ---- publish partials; single barrier; variable-width merge ----
    #pragma unroll
    for (int r = 0; r < 16; ++r) {
        const int h = (r & 3) + 8 * (r >> 2) + 4 * hi;
        Op[w][l31][h]      = o0[r];
        Op[w][l31][32 + h] = o1[r];
    }
    if (hi == 0) {
        Ml[w][l31][0] = mrun;
        Ml[w][l31][1] = lrun;
    }
    __syncthreads();

    // waves 0-3 merge tile A rows, 4-7 tile B rows; lane L = output col h
    {
        const bool tb   = (w >= 4);
        const int  base = tb ? WA : 0;
        const int  cnt  = tb ? WB : WA;
        const long oq0  = (long)(tb ? stB : stA) * 32;
        #pragma unroll
        for (int rr = 0; rr < 8; ++rr) {
            const int row = (w & 3) * 8 + rr;
            float M = -1e30f;
            for (int j = 0; j < cnt; ++j)
                M = fmaxf(M, Ml[base + j][row][0]);
            float Ls = 0.f, val = 0.f;
            for (int j = 0; j < cnt; ++j) {
                const float a = fexp2(Ml[base + j][row][0] - M);
                Ls  += a * Ml[base + j][row][1];
                val += a * Op[base + j][row][L];
            }
            out[((long)b * TT + oq0 + row) * 64 + L] = val / Ls;
        }
    }
}

extern "C" void kernel_launch(void* const* d_in, const int* in_sizes, int n_in,
                              void* d_out, int out_size, void* d_ws, size_t ws_size,
                              hipStream_t stream)
{
    const float* x  = (const float*)d_in[0];
    const float* Wq = (const float*)d_in[1];
    const float* Wk = (const float*)d_in[2];
    const float* Wv = (const float*)d_in[3];
    float* out = (float*)d_out;

    const size_t n = (size_t)BB * TT * H;   // 1,048,576 per tensor
    short* q  = (short*)d_ws;
    short* k  = q + n;
    short* vt = k + n;                      // V transposed: [B][H][T]
    short* Wb = vt + n;                     // 196,608 shorts

    pack_w  <<<dim3(96),   256, 0, stream>>>(Wq, Wk, Wv, Wb);
    proj_v2 <<<dim3(1024), 256, 0, stream>>>(x, Wb, q, k, vt);
    attn_v8 <<<dim3(256),  512, 0, stream>>>(q, k, vt, out);
}

// Round 11
// 58.273 us; speedup vs baseline: 1.1129x; 1.1129x over previous
//
#include <hip/hip_runtime.h>

#define E  1024
#define H  64
#define BB 8
#define TT 2048

typedef __attribute__((ext_vector_type(8)))  short bf16x8;
typedef __attribute__((ext_vector_type(4)))  float f32x4;
typedef __attribute__((ext_vector_type(16))) float f32x16;
typedef __attribute__((ext_vector_type(8)))  short short8;
typedef __attribute__((ext_vector_type(4)))  short short4v;
typedef __attribute__((ext_vector_type(4)))  unsigned u32x4;

__device__ __forceinline__ short f2bf(float f) {
    union { float f; unsigned u; } v; v.f = f;
    unsigned r = v.u + 0x7FFFu + ((v.u >> 16) & 1u);   // RNE
    return (short)(r >> 16);
}

// fast 2^x via the HW transcendental (no HIP __exp2f intrinsic exists)
__device__ __forceinline__ float fexp2(float x) {
    float r;
    asm("v_exp_f32 %0, %1" : "=v"(r) : "v"(x));
    return r;
}

// 8 fp32 -> bf16x8 via 4x v_cvt_pk_bf16_f32
__device__ __forceinline__ bf16x8 cvt8(float4 a0, float4 a1) {
    unsigned w0, w1, w2, w3;
    asm("v_cvt_pk_bf16_f32 %0, %1, %2" : "=v"(w0) : "v"(a0.x), "v"(a0.y));
    asm("v_cvt_pk_bf16_f32 %0, %1, %2" : "=v"(w1) : "v"(a0.z), "v"(a0.w));
    asm("v_cvt_pk_bf16_f32 %0, %1, %2" : "=v"(w2) : "v"(a1.x), "v"(a1.y));
    asm("v_cvt_pk_bf16_f32 %0, %1, %2" : "=v"(w3) : "v"(a1.z), "v"(a1.w));
    u32x4 u = {w0, w1, w2, w3};
    bf16x8 r;
    __builtin_memcpy(&r, &u, 16);
    return r;
}

// ---- pack W into B-fragment layout for mfma_f32_16x16x32_bf16 ----
__global__ __launch_bounds__(256)
void pack_w(const float* __restrict__ Wq, const float* __restrict__ Wk,
            const float* __restrict__ Wv, short* __restrict__ Wb)
{
    const int t  = blockIdx.x * 256 + threadIdx.x;   // 24576 total
    const int l  = t & 63;
    const int f  = (t >> 6) % 12;
    const int kc = t / 768;                          // kchunk 0..31
    const float* W = (f < 4) ? Wq : ((f < 8) ? Wk : Wv);
    const int e0 = kc * 32 + ((l >> 4) << 3);
    const int n  = ((f & 3) << 4) + (l & 15);
    short8 o;
    #pragma unroll
    for (int j = 0; j < 8; ++j) o[j] = f2bf(W[(e0 + j) * 64 + n]);
    *(short8*)&Wb[(size_t)t * 8] = o;
}

// ---- proj v3: LDS-staged bf16 x, no split-K, N-split across 8 waves ----
// grid 512 x 512 thr. Block = 32 rows. Stage x rows as bf16 in LDS (XOR-
// swizzled 16B units) in one up-front burst, then each wave (rg, fg)
// computes 16 rows x 3 frags over full K=1024: per kc 1 ds_read_b128 +
// 3 coalesced Wb loads (L2) + 3 MFMA. No partials, no merge.
__global__ __launch_bounds__(512)
void proj_v3(const float* __restrict__ x, const short* __restrict__ Wb,
             short* __restrict__ q, short* __restrict__ k, short* __restrict__ vt)
{
    __shared__ short xs[32 * 1024];      // 64 KB bf16 x tile
    const int t = threadIdx.x;
    const long row0 = (long)blockIdx.x * 32;

    // ---- stage: 32768 floats; 64/thread; all 16 float4 loads in flight ----
    {
        float4 va[16];
        #pragma unroll
        for (int i = 0; i < 8; ++i) {
            const int idx = i * 512 + t;
            const int row = idx >> 7, u = idx & 127;
            const float* p = x + (row0 + row) * E + u * 8;
            va[i * 2]     = *(const float4*)(p);
            va[i * 2 + 1] = *(const float4*)(p + 4);
        }
        #pragma unroll
        for (int i = 0; i < 8; ++i) {
            const int idx = i * 512 + t;
            const int row = idx >> 7, u = idx & 127;
            *(bf16x8*)&xs[row * 1024 + ((u ^ (row & 7)) << 3)] = cvt8(va[i * 2], va[i * 2 + 1]);
        }
    }
    __syncthreads();

    // ---- compute: wave (rg, fg); rows rg*16..+16, frags fg*3..+3 ----
    const int l   = t & 63;
    const int w8  = t >> 6;
    const int rg  = w8 >> 2, fg = w8 & 3;
    const int l15 = l & 15, g = l >> 4;
    const int arow  = rg * 16 + l15;
    const int abase = arow * 1024;
    const int aswz  = arow & 7;

    f32x4 acc[3] = {(f32x4){0,0,0,0}, (f32x4){0,0,0,0}, (f32x4){0,0,0,0}};
    const short* wb = Wb + ((size_t)(fg * 3) * 64 + l) * 8;

    #pragma unroll 4
    for (int kc = 0; kc < 32; ++kc) {
        bf16x8 af = *(const bf16x8*)&xs[abase + (((kc * 4 + g) ^ aswz) << 3)];
        const short* wp = wb + (size_t)kc * 12 * 512;
        bf16x8 b0 = *(const bf16x8*)(wp);
        bf16x8 b1 = *(const bf16x8*)(wp + 512);
        bf16x8 b2 = *(const bf16x8*)(wp + 1024);
        acc[0] = __builtin_amdgcn_mfma_f32_16x16x32_bf16(af, b0, acc[0], 0, 0, 0);
        acc[1] = __builtin_amdgcn_mfma_f32_16x16x32_bf16(af, b1, acc[1], 0, 0, 0);
        acc[2] = __builtin_amdgcn_mfma_f32_16x16x32_bf16(af, b2, acc[2], 0, 0, 0);
    }

    // ---- store: C frag (col=l15, row=g*4+r) ----
    const long rowb = row0 + rg * 16;
    #pragma unroll
    for (int fi = 0; fi < 3; ++fi) {
        const int f = fg * 3 + fi;
        const int m = f >> 2;
        const int h = ((f & 3) << 4) + l15;
        if (m == 2) {
            // Vt[b][h][t], 4 consecutive t in one 8B store
            const long row = rowb + g * 4;
            const long bb = row >> 11;
            const int  t0 = (int)(row & 2047);
            short4v pkt;
            #pragma unroll
            for (int r = 0; r < 4; ++r) pkt[r] = f2bf(acc[fi][r]);
            *(short4v*)&vt[(bb * 64 + h) * TT + t0] = pkt;
        } else {
            short* base = (m == 0) ? q : k;
            // fold 1/sqrt(H) AND log2(e) into q -> softmax uses exp2
            const float sc = (m == 0) ? (0.125f * 1.44269504f) : 1.0f;
            #pragma unroll
            for (int r = 0; r < 4; ++r)
                base[(rowb + g * 4 + r) * 64 + h] = f2bf(acc[fi][r] * sc);
        }
    }
}

// ---- 32x32 swapped-QK^T flash attention (T12: cvt_pk + permlane32_swap) ----
// Grid 256 = 32 tile-pairs x 8 batches (b = bid&7 -> XCD pin). Block = 512
// thr = 8 waves on tile pair (pr, 63-pr) = 65 chunks of 32 kv; waves split
// proportionally (8-10 chunks each). Swapped QK^T: lane owns q-row (L&31),
// P^T col in regs -> lane-local softmax, in-register P->bf16 B-frags.
__global__ __launch_bounds__(512)
void attn_v8(const short* __restrict__ qg,
             const short* __restrict__ kg,
             const short* __restrict__ vtg,
             float* __restrict__ out)
{
    __shared__ float Op[8][32][66];      // per-wave O^T partials [w][q][h]
    __shared__ float Ml[8][32][2];       // per-wave (m, l)

    const int t   = threadIdx.x;
    const int L   = t & 63;
    const int w   = t >> 6;
    const int bid = blockIdx.x;
    const int b   = bid & 7;             // XCD pin
    const int pr  = bid >> 3;            // pair 0..31
    const int l31 = L & 31, hi = L >> 5;

    const int stA = pr, stB = 63 - pr;
    const int nA = stA + 1;
    int WA = (8 * nA + 32) / 65;         // round(8*nA/65)
    WA = WA < 1 ? 1 : (WA > 7 ? 7 : WA);
    const int WB = 8 - WA;

    const bool isB  = (w >= WA);
    const int  st   = isB ? stB : stA;
    const int  q0   = st * 32;
    const int  strd = isB ? WB : WA;
    const int  c0   = isB ? (w - WA) : w;

    // Q B-frags: col=q=l31, k=e=es*16+hi*8+j
    bf16x8 qf[4];
    {
        const short* qp = qg + ((long)b * TT + q0 + l31) * 64 + hi * 8;
        qf[0] = *(const bf16x8*)(qp);
        qf[1] = *(const bf16x8*)(qp + 16);
        qf[2] = *(const bf16x8*)(qp + 32);
        qf[3] = *(const bf16x8*)(qp + 48);
    }

    f32x16 o0 = {}, o1 = {};
    float mrun = -1e30f, lrun = 0.f;

    const short* kbase = kg  + ((long)b * TT + l31) * 64 + hi * 8;
    const short* vbase = vtg + ((long)b * 64 + l31) * TT + hi * 8;

    for (int ci = c0; ci <= st; ci += strd) {
        const int kvs = ci * 32;
        // K A-frags: row=kv=kvs+l31, k=e (contiguous 16B)
        const short* kp = kbase + (long)kvs * 64;
        bf16x8 kf0 = *(const bf16x8*)(kp);
        bf16x8 kf1 = *(const bf16x8*)(kp + 16);
        bf16x8 kf2 = *(const bf16x8*)(kp + 32);
        bf16x8 kf3 = *(const bf16x8*)(kp + 48);
        // V A-frags issued early: row=h=nf*32+l31, k=kv slice
        const short* vp = vbase + kvs;
        bf16x8 vf00 = *(const bf16x8*)(vp);
        bf16x8 vf01 = *(const bf16x8*)(vp + 16);
        bf16x8 vf10 = *(const bf16x8*)(vp + 32 * TT);
        bf16x8 vf11 = *(const bf16x8*)(vp + 32 * TT + 16);

        // ---- QK^T swapped: S^T[kv,q]; D: col=q=l31, row=crow(r,hi) ----
        f32x16 s = {};
        __builtin_amdgcn_s_setprio(1);
        s = __builtin_amdgcn_mfma_f32_32x32x16_bf16(kf0, qf[0], s, 0, 0, 0);
        s = __builtin_amdgcn_mfma_f32_32x32x16_bf16(kf1, qf[1], s, 0, 0, 0);
        s = __builtin_amdgcn_mfma_f32_32x32x16_bf16(kf2, qf[2], s, 0, 0, 0);
        s = __builtin_amdgcn_mfma_f32_32x32x16_bf16(kf3, qf[3], s, 0, 0, 0);
        __builtin_amdgcn_s_setprio(0);

        // ---- causal mask: only the diagonal chunk ----
        if (kvs == q0) {
            #pragma unroll
            for (int r = 0; r < 16; ++r) {
                const int crow = (r & 3) + 8 * (r >> 2) + 4 * hi;
                if (crow > l31) s[r] = -1e30f;
            }
        }
        // ---- lane-local row max (q-row = l31) + hi-half exchange ----
        float m01 = fmaxf(s[0], s[1]),   m23 = fmaxf(s[2], s[3]);
        float m45 = fmaxf(s[4], s[5]),   m67 = fmaxf(s[6], s[7]);
        float m89 = fmaxf(s[8], s[9]),   mab = fmaxf(s[10], s[11]);
        float mcd = fmaxf(s[12], s[13]), mef = fmaxf(s[14], s[15]);
        float mloc = fmaxf(fmaxf(fmaxf(m01, m23), fmaxf(m45, m67)),
                           fmaxf(fmaxf(m89, mab), fmaxf(mcd, mef)));
        mloc = fmaxf(mloc, __shfl_xor(mloc, 32));
        // ---- defer-max rescale (THR = 8 in exp2 units) ----
        if (__any(mloc > mrun + 8.f)) {
            const float mnew = fmaxf(mrun, mloc);
            const float a = fexp2(mrun - mnew);
            mrun = mnew;
            lrun *= a;
            #pragma unroll
            for (int r = 0; r < 16; ++r) { o0[r] *= a; o1[r] *= a; }
        }
        // ---- p = exp2(s - m) in place; lane-local sum ----
        #pragma unroll
        for (int r = 0; r < 16; ++r) s[r] = fexp2(s[r] - mrun);
        {
            float s01 = (s[0] + s[1]) + (s[2] + s[3]);
            float s23 = (s[4] + s[5]) + (s[6] + s[7]);
            float s45 = (s[8] + s[9]) + (s[10] + s[11]);
            float s67 = (s[12] + s[13]) + (s[14] + s[15]);
            float lsum = (s01 + s23) + (s45 + s67);
            lsum += __shfl_xor(lsum, 32);
            lrun += lsum;
        }
        // ---- in-register P->bf16 B-frags: 8 cvt_pk + 4 permlane32_swap ----
        unsigned wv[8];
        #pragma unroll
        for (int i = 0; i < 8; ++i)
            asm("v_cvt_pk_bf16_f32 %0, %1, %2" : "=v"(wv[i]) : "v"(s[2 * i]), "v"(s[2 * i + 1]));
        unsigned p00 = wv[0], p02 = wv[2];   // ks=0: words 0,2
        unsigned p01 = wv[1], p03 = wv[3];   // ks=0: words 1,3
        unsigned p10 = wv[4], p12 = wv[6];   // ks=1
        unsigned p11 = wv[5], p13 = wv[7];
        asm("v_permlane32_swap_b32 %0, %1" : "+v"(p00), "+v"(p02));
        asm("v_permlane32_swap_b32 %0, %1" : "+v"(p01), "+v"(p03));
        asm("v_permlane32_swap_b32 %0, %1" : "+v"(p10), "+v"(p12));
        asm("v_permlane32_swap_b32 %0, %1" : "+v"(p11), "+v"(p13));
        u32x4 pb0u = {p00, p01, p02, p03};
        u32x4 pb1u = {p10, p11, p12, p13};
        bf16x8 pb0, pb1;
        __builtin_memcpy(&pb0, &pb0u, 16);
        __builtin_memcpy(&pb1, &pb1u, 16);
        // ---- PV: O^T[h,q] += V^T x P^T ----
        __builtin_amdgcn_s_setprio(1);
        o0 = __builtin_amdgcn_mfma_f32_32x32x16_bf16(vf00, pb0, o0, 0, 0, 0);
        o0 = __builtin_amdgcn_mfma_f32_32x32x16_bf16(vf01, pb1, o0, 0, 0, 0);
        o1 = __builtin_amdgcn_mfma_f32_32x32x16_bf16(vf10, pb0, o1, 0, 0, 0);
        o1 = __builtin_amdgcn_mfma_f32_32x32x16_bf16(vf11, pb1, o1, 0, 0, 0);
        __builtin_amdgcn_s_setprio(0);
    }

    // ---- publish partials; single barrier; variable-width merge ----
    #pragma unroll
    for (int r = 0; r < 16; ++r) {
        const int h = (r & 3) + 8 * (r >> 2) + 4 * hi;
        Op[w][l31][h]      = o0[r];
        Op[w][l31][32 + h] = o1[r];
    }
    if (hi == 0) {
        Ml[w][l31][0] = mrun;
        Ml[w][l31][1] = lrun;
    }
    __syncthreads();

    // waves 0-3 merge tile A rows, 4-7 tile B rows; lane L = output col h
    {
        const bool tb   = (w >= 4);
        const int  base = tb ? WA : 0;
        const int  cnt  = tb ? WB : WA;
        const long oq0  = (long)(tb ? stB : stA) * 32;
        #pragma unroll
        for (int rr = 0; rr < 8; ++rr) {
            const int row = (w & 3) * 8 + rr;
            float M = -1e30f;
            for (int j = 0; j < cnt; ++j)
                M = fmaxf(M, Ml[base + j][row][0]);
            float Ls = 0.f, val = 0.f;
            for (int j = 0; j < cnt; ++j) {
                const float a = fexp2(Ml[base + j][row][0] - M);
                Ls  += a * Ml[base + j][row][1];
                val += a * Op[base + j][row][L];
            }
            out[((long)b * TT + oq0 + row) * 64 + L] = val / Ls;
        }
    }
}

extern "C" void kernel_launch(void* const* d_in, const int* in_sizes, int n_in,
                              void* d_out, int out_size, void* d_ws, size_t ws_size,
                              hipStream_t stream)
{
    const float* x  = (const float*)d_in[0];
    const float* Wq = (const float*)d_in[1];
    const float* Wk = (const float*)d_in[2];
    const float* Wv = (const float*)d_in[3];
    float* out = (float*)d_out;

    const size_t n = (size_t)BB * TT * H;   // 1,048,576 per tensor
    short* q  = (short*)d_ws;
    short* k  = q + n;
    short* vt = k + n;                      // V transposed: [B][H][T]
    short* Wb = vt + n;                     // 196,608 shorts

    pack_w  <<<dim3(96),  256, 0, stream>>>(Wq, Wk, Wv, Wb);
    proj_v3 <<<dim3(512), 512, 0, stream>>>(x, Wb, q, k, vt);
    attn_v8 <<<dim3(256), 512, 0, stream>>>(q, k, vt, out);
}